// Round 2
// baseline (20005.800 us; speedup 1.0000x reference)
//
#include <hip/hip_runtime.h>
#include <hip/hip_fp16.h>

#define H 1024
#define B 512
#define T 512
#define NC 10

#define NGROUPS 16   // batch-slice groups
#define WPG 32       // WGs per group (M slices)
#define NSLICE 32    // batches per group
#define MROWS 32     // H rows per WG

typedef _Float16 f16x8 __attribute__((ext_vector_type(8)));
typedef _Float16 f16x4 __attribute__((ext_vector_type(4)));
typedef float    f32x4 __attribute__((ext_vector_type(4)));

__device__ __forceinline__ float fast_tanh(float x) {
    float e = __expf(2.0f * x);
    return 1.0f - 2.0f / (e + 1.0f);
}

// ---- x [B][T] -> xT [T][B] (f32), LDS-tiled transpose ----
__global__ void transpose_x(const float* __restrict__ x, float* __restrict__ xT) {
    __shared__ float tile[32][33];
    const int tx = threadIdx.x & 31;
    const int ty = threadIdx.x >> 5;          // 0..7
    const int t0 = blockIdx.x * 32;
    const int b0 = blockIdx.y * 32;
    #pragma unroll
    for (int i = ty; i < 32; i += 8)
        tile[i][tx] = x[(size_t)(b0 + i) * T + t0 + tx];
    __syncthreads();
    #pragma unroll
    for (int i = ty; i < 32; i += 8)
        xT[(size_t)(t0 + i) * B + b0 + tx] = tile[tx][i];
}

// ---- persistent RNN: 512 WGs (16 groups x 32 M-slices), 1 wave each ----
// W rows for this WG live in LDS (f16, XOR-swizzled). h ping-pongs in global.
// Per step: h_new[n][m] = tanh( sum_k W[m][k]*h_old[n][k] + Whx[m]*xT[t][n] + bh[n] )
__global__ void __launch_bounds__(64, 1) rnn_persist(
        const float* __restrict__ Whh, const float* __restrict__ xT,
        const float* __restrict__ Whx, const float* __restrict__ bh,
        _Float16* __restrict__ h0, _Float16* __restrict__ h1,
        unsigned* __restrict__ cnt) {

    __shared__ _Float16 Wlds[MROWS * H];   // 64 KB exactly -> 2 WGs/CU

    const int wg   = blockIdx.x;     // 0..511
    const int g    = wg >> 5;        // group 0..15 (batch slice)
    const int ms   = wg & 31;        // M slice 0..31
    const int lane = threadIdx.x;    // 0..63
    const int lm   = lane & 15;
    const int kg   = lane >> 4;

    // ---- stage W rows [ms*32, ms*32+32) f32->f16 into swizzled LDS ----
    {
        const int r    = lane >> 1;       // 0..31
        const int half = lane & 1;        // 0/1 -> cols [half*512, half*512+512)
        const float* src = Whh + (size_t)(ms * MROWS + r) * H + half * 512;
        const int xr = (r & 7) << 4;      // XOR swizzle for this row
        for (int c = 0; c < 512; c += 4) {
            float4 v = *(const float4*)(src + c);
            f16x4 o;
            o[0] = (_Float16)v.x; o[1] = (_Float16)v.y;
            o[2] = (_Float16)v.z; o[3] = (_Float16)v.w;
            int kbyte = (half * 512 + c) * 2;
            *(f16x4*)((char*)Wlds + r * 2048 + (kbyte ^ xr)) = o;
        }
    }
    __syncthreads();

    // ---- preload per-lane constants ----
    const int nb = g * NSLICE;
    float whx[2][4];
    #pragma unroll
    for (int fm = 0; fm < 2; ++fm)
        #pragma unroll
        for (int r = 0; r < 4; ++r)
            whx[fm][r] = Whx[ms * MROWS + fm * 16 + kg * 4 + r];
    float bhv[2];
    #pragma unroll
    for (int fn = 0; fn < 2; ++fn)
        bhv[fn] = bh[nb + fn * 16 + lm];

    const int xr = (lm & 7) << 4;

    const _Float16* hin = h0;
    _Float16* hout = h1;

    for (int t = 0; t < T; ++t) {
        f32x4 acc00 = 0.f, acc01 = 0.f, acc10 = 0.f, acc11 = 0.f;
        const _Float16* B0 = hin + (size_t)(nb + lm) * H + kg * 8;
        const _Float16* B1 = B0 + 16 * H;

        #pragma unroll 4
        for (int kk = 0; kk < H; kk += 32) {
            const int kbyte = kk * 2 + kg * 16;
            f16x8 a0 = *(const f16x8*)((const char*)Wlds + lm * 2048        + (kbyte ^ xr));
            f16x8 a1 = *(const f16x8*)((const char*)Wlds + (16 + lm) * 2048 + (kbyte ^ xr));
            f16x8 b0 = *(const f16x8*)(B0 + kk);
            f16x8 b1 = *(const f16x8*)(B1 + kk);
            acc00 = __builtin_amdgcn_mfma_f32_16x16x32_f16(a0, b0, acc00, 0, 0, 0);
            acc01 = __builtin_amdgcn_mfma_f32_16x16x32_f16(a0, b1, acc01, 0, 0, 0);
            acc10 = __builtin_amdgcn_mfma_f32_16x16x32_f16(a1, b0, acc10, 0, 0, 0);
            acc11 = __builtin_amdgcn_mfma_f32_16x16x32_f16(a1, b1, acc11, 0, 0, 0);
        }

        // ---- epilogue: bias + rank-1 input + tanh, store f16 ----
        f32x4 accs[2][2] = { {acc00, acc01}, {acc10, acc11} };
        float xn[2];
        #pragma unroll
        for (int fn = 0; fn < 2; ++fn)
            xn[fn] = xT[(size_t)t * B + nb + fn * 16 + lm];
        #pragma unroll
        for (int fn = 0; fn < 2; ++fn) {
            const int n = nb + fn * 16 + lm;
            #pragma unroll
            for (int fm = 0; fm < 2; ++fm) {
                const int mb = ms * MROWS + fm * 16 + kg * 4;
                f16x4 sv;
                #pragma unroll
                for (int r = 0; r < 4; ++r) {
                    float pre = accs[fm][fn][r] + whx[fm][r] * xn[fn] + bhv[fn];
                    sv[r] = (_Float16)fast_tanh(pre);
                }
                *(f16x4*)(hout + (size_t)n * H + mb) = sv;
            }
        }

        // ---- group barrier: all 32 WGs of this group done with step t ----
        __builtin_amdgcn_fence(__ATOMIC_RELEASE, "agent");   // drain + wb L2
        const unsigned tgt = (unsigned)WPG * (t + 1);
        if (lane == 0) {
            __hip_atomic_fetch_add(&cnt[g], 1u, __ATOMIC_RELAXED, __HIP_MEMORY_SCOPE_AGENT);
            while (__hip_atomic_load(&cnt[g], __ATOMIC_RELAXED, __HIP_MEMORY_SCOPE_AGENT) < tgt)
                __builtin_amdgcn_s_sleep(2);
        }
        __builtin_amdgcn_fence(__ATOMIC_ACQUIRE, "agent");   // inv L1/L2

        _Float16* tmp = (_Float16*)hin;
        hin = hout;
        hout = tmp;
    }
}

// ---- final projection: out[b][c] = sum_h Wph[c][h] * hT[b][h] + bp[b] ----
__global__ void proj_kernel(const _Float16* __restrict__ hT,
                            const float* __restrict__ Wph,
                            const float* __restrict__ bp,
                            float* __restrict__ out) {
    const int b = blockIdx.x;
    const int lane = threadIdx.x;  // 64
    float partial[NC];
    #pragma unroll
    for (int c = 0; c < NC; ++c) partial[c] = 0.f;
    for (int h = lane; h < H; h += 64) {
        float hv = (float)hT[(size_t)b * H + h];
        #pragma unroll
        for (int c = 0; c < NC; ++c) partial[c] += Wph[(size_t)c * H + h] * hv;
    }
    #pragma unroll
    for (int c = 0; c < NC; ++c) {
        float v = partial[c];
        #pragma unroll
        for (int off = 32; off; off >>= 1) v += __shfl_down(v, off);
        if (lane == 0) out[(size_t)b * NC + c] = v + bp[b];
    }
}

extern "C" void kernel_launch(void* const* d_in, const int* in_sizes, int n_in,
                              void* d_out, int out_size, void* d_ws, size_t ws_size,
                              hipStream_t stream) {
    const float* x   = (const float*)d_in[0];
    const float* Whx = (const float*)d_in[1];
    const float* Whh = (const float*)d_in[2];
    const float* Wph = (const float*)d_in[3];
    const float* bh  = (const float*)d_in[4];
    const float* bp  = (const float*)d_in[5];
    float* out = (float*)d_out;

    char* ws = (char*)d_ws;
    _Float16* h0 = (_Float16*)ws;                               // 1 MB
    _Float16* h1 = (_Float16*)(ws + (size_t)B * H * 2);         // 1 MB
    float*    xT = (float*)(ws + 2 * (size_t)B * H * 2);        // 1 MB
    unsigned* cnt = (unsigned*)(ws + 2 * (size_t)B * H * 2 + (size_t)T * B * 4);

    hipMemsetAsync(h0, 0, (size_t)B * H * 2, stream);
    hipMemsetAsync(cnt, 0, NGROUPS * sizeof(unsigned), stream);

    transpose_x<<<dim3(T / 32, B / 32), 256, 0, stream>>>(x, xT);

    rnn_persist<<<NGROUPS * WPG, 64, 0, stream>>>(Whh, xT, Whx, bh, h0, h1, cnt);

    // T even -> final h in h0
    proj_kernel<<<B, 64, 0, stream>>>(h0, Wph, bp, out);
}

// Round 3
// 9006.808 us; speedup vs baseline: 2.2212x; 2.2212x over previous
//
#include <hip/hip_runtime.h>
#include <hip/hip_fp16.h>

#define H 1024
#define B 512
#define T 512
#define NC 10

#define NGROUPS 16   // batch-slice groups (32 batches each)
#define WPG 32       // WGs per group (32 M-slices)
#define NSLICE 32    // batches per group
#define MROWS 32     // H rows per WG
#define CNT_STRIDE 32  // pad counters to separate 128B lines

typedef _Float16 f16x8 __attribute__((ext_vector_type(8)));
typedef _Float16 f16x4 __attribute__((ext_vector_type(4)));
typedef float    f32x4 __attribute__((ext_vector_type(4)));

__device__ __forceinline__ float fast_tanh(float x) {
    float e = __expf(2.0f * x);
    return 1.0f - 2.0f / (e + 1.0f);
}

// ---- x [B][T] -> xT [T][B] (f32) ----
__global__ void transpose_x(const float* __restrict__ x, float* __restrict__ xT) {
    __shared__ float tile[32][33];
    const int tx = threadIdx.x & 31;
    const int ty = threadIdx.x >> 5;
    const int t0 = blockIdx.x * 32;
    const int b0 = blockIdx.y * 32;
    #pragma unroll
    for (int i = ty; i < 32; i += 8)
        tile[i][tx] = x[(size_t)(b0 + i) * T + t0 + tx];
    __syncthreads();
    #pragma unroll
    for (int i = ty; i < 32; i += 8)
        xT[(size_t)(t0 + i) * B + b0 + tx] = tile[tx][i];
}

// ---- persistent RNN ----
// 512 WGs x 128 threads (2 waves). WG = (group g, M-slice ms).
// Wave w handles batches [g*32 + w*16, +16), rows [ms*32, +32).
// W rows in LDS (f16, XOR-swizzled). h ping-pongs in global, accessed ONLY
// via agent-scope atomics (sc0/sc1 -> coherent at Infinity Cache, no L2 flushes).
__global__ void __launch_bounds__(128, 1) rnn_persist(
        const float* __restrict__ Whh, const float* __restrict__ xT,
        const float* __restrict__ Whx, const float* __restrict__ bh,
        _Float16* __restrict__ h0, _Float16* __restrict__ h1,
        unsigned* __restrict__ cnt) {

    __shared__ _Float16 Wlds[MROWS * H];   // 64 KB -> 2 WGs/CU, 4 waves/CU

    const int wg   = blockIdx.x;       // 0..511
    const int g    = wg >> 5;          // group 0..15
    const int ms   = wg & 31;          // M slice 0..31
    const int tid  = threadIdx.x;      // 0..127
    const int wave = tid >> 6;         // 0..1
    const int lane = tid & 63;
    const int lm   = lane & 15;
    const int kg   = lane >> 4;

    // ---- stage W rows [ms*32, +32) f32->f16 into swizzled LDS (128 threads) ----
    {
        const int r = tid >> 2;            // 0..31
        const int q = tid & 3;             // quarter of the row
        const float* src = Whh + (size_t)(ms * MROWS + r) * H + q * 256;
        const int xw = (r & 7) << 4;
        for (int c = 0; c < 256; c += 4) {
            float4 v = *(const float4*)(src + c);
            f16x4 o;
            o[0] = (_Float16)v.x; o[1] = (_Float16)v.y;
            o[2] = (_Float16)v.z; o[3] = (_Float16)v.w;
            int kbyte = (q * 256 + c) * 2;
            *(f16x4*)((char*)Wlds + r * 2048 + (kbyte ^ xw)) = o;
        }
    }
    __syncthreads();

    // ---- per-lane constants ----
    const int n = g * NSLICE + wave * 16 + lm;   // this lane's batch column
    float whx0[4], whx1[4];
    #pragma unroll
    for (int r = 0; r < 4; ++r) {
        whx0[r] = Whx[ms * MROWS + kg * 4 + r];
        whx1[r] = Whx[ms * MROWS + 16 + kg * 4 + r];
    }
    const float bhn = bh[n];
    const int xr = (lm & 7) << 4;

    const _Float16* hin = h0;
    _Float16* hout = h1;
    unsigned* cg = cnt + g * CNT_STRIDE;

    for (int t = 0; t < T; ++t) {
        f32x4 acc0 = 0.f, acc1 = 0.f;
        const _Float16* Bp = hin + (size_t)n * H + kg * 8;

        #pragma unroll 8
        for (int kk = 0; kk < H; kk += 32) {
            const int kbyte = kk * 2 + kg * 16;
            f16x8 a0 = *(const f16x8*)((const char*)Wlds + lm * 2048        + (kbyte ^ xr));
            f16x8 a1 = *(const f16x8*)((const char*)Wlds + (16 + lm) * 2048 + (kbyte ^ xr));
            union { unsigned long long u[2]; f16x8 v; } bb;
            bb.u[0] = __hip_atomic_load((const unsigned long long*)(Bp + kk),
                                        __ATOMIC_RELAXED, __HIP_MEMORY_SCOPE_AGENT);
            bb.u[1] = __hip_atomic_load((const unsigned long long*)(Bp + kk + 4),
                                        __ATOMIC_RELAXED, __HIP_MEMORY_SCOPE_AGENT);
            acc0 = __builtin_amdgcn_mfma_f32_16x16x32_f16(a0, bb.v, acc0, 0, 0, 0);
            acc1 = __builtin_amdgcn_mfma_f32_16x16x32_f16(a1, bb.v, acc1, 0, 0, 0);
        }

        // ---- epilogue: rank-1 input + bias + tanh, coherent 8B stores ----
        const float xn = xT[(size_t)t * B + n];
        union { unsigned long long u; f16x4 v; } s0, s1;
        #pragma unroll
        for (int r = 0; r < 4; ++r)
            s0.v[r] = (_Float16)fast_tanh(acc0[r] + whx0[r] * xn + bhn);
        #pragma unroll
        for (int r = 0; r < 4; ++r)
            s1.v[r] = (_Float16)fast_tanh(acc1[r] + whx1[r] * xn + bhn);
        const int mb = ms * MROWS + kg * 4;
        __hip_atomic_store((unsigned long long*)(hout + (size_t)n * H + mb), s0.u,
                           __ATOMIC_RELAXED, __HIP_MEMORY_SCOPE_AGENT);
        __hip_atomic_store((unsigned long long*)(hout + (size_t)n * H + mb + 16), s1.u,
                           __ATOMIC_RELAXED, __HIP_MEMORY_SCOPE_AGENT);

        // ---- group barrier: 64 waves/group, no cache-maintenance ops ----
        asm volatile("s_waitcnt vmcnt(0)" ::: "memory");  // stores ack'd at MALL
        const unsigned tgt = (unsigned)(WPG * 2) * (t + 1);
        if (lane == 0)
            __hip_atomic_fetch_add(cg, 1u, __ATOMIC_RELAXED, __HIP_MEMORY_SCOPE_AGENT);
        while (__hip_atomic_load(cg, __ATOMIC_RELAXED, __HIP_MEMORY_SCOPE_AGENT) < tgt)
            __builtin_amdgcn_s_sleep(2);
        __builtin_amdgcn_sched_barrier(0);
        asm volatile("" ::: "memory");

        _Float16* tmp = (_Float16*)hin;
        hin = hout;
        hout = tmp;
    }
}

// ---- final projection ----
__global__ void proj_kernel(const _Float16* __restrict__ hT,
                            const float* __restrict__ Wph,
                            const float* __restrict__ bp,
                            float* __restrict__ out) {
    const int b = blockIdx.x;
    const int lane = threadIdx.x;  // 64
    float partial[NC];
    #pragma unroll
    for (int c = 0; c < NC; ++c) partial[c] = 0.f;
    for (int h = lane; h < H; h += 64) {
        float hv = (float)hT[(size_t)b * H + h];
        #pragma unroll
        for (int c = 0; c < NC; ++c) partial[c] += Wph[(size_t)c * H + h] * hv;
    }
    #pragma unroll
    for (int c = 0; c < NC; ++c) {
        float v = partial[c];
        #pragma unroll
        for (int off = 32; off; off >>= 1) v += __shfl_down(v, off);
        if (lane == 0) out[(size_t)b * NC + c] = v + bp[b];
    }
}

extern "C" void kernel_launch(void* const* d_in, const int* in_sizes, int n_in,
                              void* d_out, int out_size, void* d_ws, size_t ws_size,
                              hipStream_t stream) {
    const float* x   = (const float*)d_in[0];
    const float* Whx = (const float*)d_in[1];
    const float* Whh = (const float*)d_in[2];
    const float* Wph = (const float*)d_in[3];
    const float* bh  = (const float*)d_in[4];
    const float* bp  = (const float*)d_in[5];
    float* out = (float*)d_out;

    char* ws = (char*)d_ws;
    _Float16* h0 = (_Float16*)ws;                               // 1 MB
    _Float16* h1 = (_Float16*)(ws + (size_t)B * H * 2);         // 1 MB
    float*    xT = (float*)(ws + 2 * (size_t)B * H * 2);        // 1 MB
    unsigned* cnt = (unsigned*)(ws + 2 * (size_t)B * H * 2 + (size_t)T * B * 4);

    hipMemsetAsync(h0, 0, (size_t)B * H * 2, stream);
    hipMemsetAsync(cnt, 0, NGROUPS * CNT_STRIDE * sizeof(unsigned), stream);

    transpose_x<<<dim3(T / 32, B / 32), 256, 0, stream>>>(x, xT);

    rnn_persist<<<NGROUPS * WPG, 128, 0, stream>>>(Whh, xT, Whx, bh, h0, h1, cnt);

    // T even -> final h back in h0
    proj_kernel<<<B, 64, 0, stream>>>(h0, Wph, bp, out);
}

// Round 4
// 5349.006 us; speedup vs baseline: 3.7401x; 1.6838x over previous
//
#include <hip/hip_runtime.h>
#include <hip/hip_fp16.h>

#define H 1024
#define B 512
#define T 512
#define NC 10

#define NGROUPS 16      // batch-slice groups (32 batches each)
#define NSLICE 32       // batches per group
#define WPG 16          // WGs per group (M slices)
#define MROWS 64        // H rows per WG
#define WAVES_PER_GROUP (WPG * 4)
#define CNT_STRIDE 32   // pad counters to separate lines

typedef _Float16 f16x8 __attribute__((ext_vector_type(8)));
typedef _Float16 f16x4 __attribute__((ext_vector_type(4)));
typedef float    f32x4 __attribute__((ext_vector_type(4)));

__device__ __forceinline__ float fast_tanh(float x) {
    float e = __expf(2.0f * x);
    return 1.0f - 2.0f / (e + 1.0f);
}

// ---- W_hh f32 -> f16 row-major ----
__global__ void convert_w(const float* __restrict__ w, _Float16* __restrict__ o) {
    int i = (blockIdx.x * 256 + threadIdx.x) * 4;
    float4 v = *(const float4*)(w + i);
    f16x4 r;
    r[0] = (_Float16)v.x; r[1] = (_Float16)v.y;
    r[2] = (_Float16)v.z; r[3] = (_Float16)v.w;
    *(f16x4*)(o + i) = r;
}

// ---- x [B][T] -> xT [T][B] ----
__global__ void transpose_x(const float* __restrict__ x, float* __restrict__ xT) {
    __shared__ float tile[32][33];
    const int tx = threadIdx.x & 31;
    const int ty = threadIdx.x >> 5;
    const int t0 = blockIdx.x * 32;
    const int b0 = blockIdx.y * 32;
    #pragma unroll
    for (int i = ty; i < 32; i += 8)
        tile[i][tx] = x[(size_t)(b0 + i) * T + t0 + tx];
    __syncthreads();
    #pragma unroll
    for (int i = ty; i < 32; i += 8)
        xT[(size_t)(t0 + i) * B + b0 + tx] = tile[tx][i];
}

// ---- persistent RNN ----
// 256 WGs x 256 threads (4 waves): WG = (group g, M-slice ms); grid == CU count.
// Wave (wm,wn): rows [ms*64 + wm*32, +32), batches [g*32 + wn*16, +16).
// W in LDS in MFMA-fragment order (conflict-free b128 reads).
// h in fragment-order global layout: write-through coherent stores (sc0sc1),
// plain CACHED loads + per-step acquire fence (buffer_inv, no wb) by wave 0.
__global__ void __launch_bounds__(256, 1) rnn_persist(
        const _Float16* __restrict__ Wf, const float* __restrict__ xT,
        const float* __restrict__ Whx, const float* __restrict__ bh,
        _Float16* h0, _Float16* h1, unsigned* cnt) {

    __shared__ _Float16 Wlds[MROWS * H];   // 128 KB -> 1 WG/CU, 4 waves/CU

    // XCD-aware swizzle (perf-only): co-locate each group's 16 WGs
    const int bid = blockIdx.x;
    const int xcd = bid & 7;
    const int j   = bid >> 3;              // 0..31
    const int g   = (xcd << 1) | (j >> 4); // group 0..15
    const int ms  = j & 15;                // M slice 0..15

    const int tid  = threadIdx.x;
    const int wave = tid >> 6;
    const int lane = tid & 63;
    const int wm   = wave >> 1;            // M half 0..1
    const int wn   = wave & 1;             // N half 0..1
    const int lm   = lane & 15;
    const int kg   = lane >> 4;

    // ---- stage W into fragment-order LDS ----
    // plane p = kkblk*4 + wm*2 + rb (1 KB each); fragment = plane*64 + lane
    for (int f = tid; f < MROWS * H / 8; f += 256) {
        const int p   = f >> 6;
        const int l   = f & 63;
        const int kkb = p >> 2;
        const int pwm = (p >> 1) & 1;
        const int prb = p & 1;
        const int pkg = l >> 4;
        const int plm = l & 15;
        const int m = ms * 64 + pwm * 32 + prb * 16 + plm;
        f16x8 v = *(const f16x8*)(Wf + (size_t)m * H + kkb * 32 + pkg * 8);
        *(f16x8*)((char*)Wlds + (size_t)f * 16) = v;
    }
    __syncthreads();

    // ---- per-lane constants ----
    const int n      = g * NSLICE + wn * 16 + lm;   // batch column
    const int base32 = ms * 64 + wm * 32;
    float whx0[4], whx1[4];
    #pragma unroll
    for (int r = 0; r < 4; ++r) {
        whx0[r] = Whx[base32 + kg * 4 + r];
        whx1[r] = Whx[base32 + 16 + kg * 4 + r];
    }
    const float bhn = bh[n];
    // consumer B-frag byte offsets within each 64B block (fragment-order h)
    const int off0 = ((kg & 1) << 5) | ((kg >> 1) << 3);

    const char* hin  = (const char*)h0;
    char*       hout = (char*)h1;
    unsigned*   cg   = cnt + g * CNT_STRIDE;

    for (int t = 0; t < T; ++t) {
        f32x4 acc0 = {0.f, 0.f, 0.f, 0.f};
        f32x4 acc1 = {0.f, 0.f, 0.f, 0.f};
        const char* brow = hin + (size_t)n * 2048;
        const char* arow = (const char*)Wlds + wm * 2048 + lane * 16;

        #pragma unroll 8
        for (int kb = 0; kb < 32; ++kb) {
            f16x8 a0 = *(const f16x8*)(arow + kb * 4096);
            f16x8 a1 = *(const f16x8*)(arow + kb * 4096 + 1024);
            union { unsigned long long u[2]; f16x8 v; } bb;
            bb.u[0] = *(const unsigned long long*)(brow + kb * 64 + off0);
            bb.u[1] = *(const unsigned long long*)(brow + kb * 64 + off0 + 16);
            acc0 = __builtin_amdgcn_mfma_f32_16x16x32_f16(a0, bb.v, acc0, 0, 0, 0);
            acc1 = __builtin_amdgcn_mfma_f32_16x16x32_f16(a1, bb.v, acc1, 0, 0, 0);
        }

        // ---- epilogue: rank-1 input + bias + tanh ----
        const float xn = xT[(size_t)t * B + n];
        union { unsigned long long u; f16x4 v; } s0, s1;
        #pragma unroll
        for (int r = 0; r < 4; ++r)
            s0.v[r] = (_Float16)fast_tanh(acc0[r] + whx0[r] * xn + bhn);
        #pragma unroll
        for (int r = 0; r < 4; ++r)
            s1.v[r] = (_Float16)fast_tanh(acc1[r] + whx1[r] * xn + bhn);
        // fragment-order store: 16B contiguous per lane, coherent write-through
        char* dst = hout + (size_t)n * 2048 + (ms * 2 + wm) * 64 + kg * 16;
        __hip_atomic_store((unsigned long long*)dst, s0.u,
                           __ATOMIC_RELAXED, __HIP_MEMORY_SCOPE_AGENT);
        __hip_atomic_store((unsigned long long*)(dst + 8), s1.u,
                           __ATOMIC_RELAXED, __HIP_MEMORY_SCOPE_AGENT);

        // ---- group barrier ----
        asm volatile("s_waitcnt vmcnt(0)" ::: "memory");   // stores at coherence point
        if (lane == 0)
            __hip_atomic_fetch_add(cg, 1u, __ATOMIC_RELAXED, __HIP_MEMORY_SCOPE_AGENT);
        const unsigned tgt = (unsigned)WAVES_PER_GROUP * (t + 1);
        if (wave == 0) {
            while (__hip_atomic_load(cg, __ATOMIC_RELAXED, __HIP_MEMORY_SCOPE_AGENT) < tgt)
                __builtin_amdgcn_s_sleep(1);
            // acquire: invalidate L1+L2 (nothing dirty -> no writeback storm)
            __builtin_amdgcn_fence(__ATOMIC_ACQUIRE, "agent");
        }
        __syncthreads();   // releases waves 1..3 after inv completes
        __builtin_amdgcn_sched_barrier(0);

        char* tmp = (char*)hin;
        hin = hout;
        hout = tmp;
    }
}

// ---- final projection (reads fragment-order h) ----
__global__ void proj_kernel(const _Float16* __restrict__ hbuf,
                            const float* __restrict__ Wph,
                            const float* __restrict__ bp,
                            float* __restrict__ out) {
    const int b = blockIdx.x;
    const int lane = threadIdx.x;  // 64
    float partial[NC];
    #pragma unroll
    for (int c = 0; c < NC; ++c) partial[c] = 0.f;
    for (int i = lane; i < H; i += 64) {
        const int inner = i & 31;           // element within 32-row block
        const int pkg = inner >> 3;
        const int prb = (inner >> 2) & 1;
        const int pr  = inner & 3;
        const int m = (i >> 5) * 32 + prb * 16 + pkg * 4 + pr;
        float hv = (float)hbuf[(size_t)b * H + i];
        #pragma unroll
        for (int c = 0; c < NC; ++c) partial[c] += Wph[(size_t)c * H + m] * hv;
    }
    #pragma unroll
    for (int c = 0; c < NC; ++c) {
        float v = partial[c];
        #pragma unroll
        for (int off = 32; off; off >>= 1) v += __shfl_down(v, off);
        if (lane == 0) out[(size_t)b * NC + c] = v + bp[b];
    }
}

extern "C" void kernel_launch(void* const* d_in, const int* in_sizes, int n_in,
                              void* d_out, int out_size, void* d_ws, size_t ws_size,
                              hipStream_t stream) {
    const float* x   = (const float*)d_in[0];
    const float* Whx = (const float*)d_in[1];
    const float* Whh = (const float*)d_in[2];
    const float* Wph = (const float*)d_in[3];
    const float* bh  = (const float*)d_in[4];
    const float* bp  = (const float*)d_in[5];
    float* out = (float*)d_out;

    char* ws = (char*)d_ws;
    _Float16* Wf  = (_Float16*)ws;                           // 2 MB
    _Float16* h0  = (_Float16*)(ws + (2u << 20));            // 1 MB
    _Float16* h1  = (_Float16*)(ws + (3u << 20));            // 1 MB
    float*    xT  = (float*)(ws + (4u << 20));               // 1 MB
    unsigned* cnt = (unsigned*)(ws + (5u << 20));

    convert_w<<<(H * H / 4) / 256, 256, 0, stream>>>(Whh, Wf);
    transpose_x<<<dim3(T / 32, B / 32), 256, 0, stream>>>(x, xT);
    hipMemsetAsync(h0, 0, (size_t)B * H * 2, stream);
    hipMemsetAsync(cnt, 0, NGROUPS * CNT_STRIDE * sizeof(unsigned), stream);

    rnn_persist<<<NGROUPS * WPG, 256, 0, stream>>>(Wf, xT, Whx, bh, h0, h1, cnt);

    // T even -> final h back in h0
    proj_kernel<<<B, 64, 0, stream>>>(h0, Wph, bp, out);
}

// Round 6
// 5099.424 us; speedup vs baseline: 3.9231x; 1.0489x over previous
//
#include <hip/hip_runtime.h>
#include <hip/hip_fp16.h>

#define H 1024
#define B 512
#define T 512
#define NC 10

#define NGROUPS 16      // batch-slice groups (32 batches each)
#define NSLICE 32       // batches per group
#define WPG 16          // WGs per group (M slices)
#define MROWS 64        // H rows per WG
#define FLAG_STRIDE 16  // 64B-padded flag per WG

typedef _Float16 f16x8 __attribute__((ext_vector_type(8)));
typedef _Float16 f16x4 __attribute__((ext_vector_type(4)));
typedef float    f32x4 __attribute__((ext_vector_type(4)));
typedef unsigned long long ull;

__device__ __forceinline__ float fast_tanh(float x) {
    float e = __expf(2.0f * x);
    return 1.0f - 2.0f / (e + 1.0f);
}

// ---- W_hh f32 -> f16 row-major ----
__global__ void convert_w(const float* __restrict__ w, _Float16* __restrict__ o) {
    int i = (blockIdx.x * 256 + threadIdx.x) * 4;
    float4 v = *(const float4*)(w + i);
    f16x4 r;
    r[0] = (_Float16)v.x; r[1] = (_Float16)v.y;
    r[2] = (_Float16)v.z; r[3] = (_Float16)v.w;
    *(f16x4*)(o + i) = r;
}

// ---- x [B][T] -> xT [T][B] ----
__global__ void transpose_x(const float* __restrict__ x, float* __restrict__ xT) {
    __shared__ float tile[32][33];
    const int tx = threadIdx.x & 31;
    const int ty = threadIdx.x >> 5;
    const int t0 = blockIdx.x * 32;
    const int b0 = blockIdx.y * 32;
    #pragma unroll
    for (int i = ty; i < 32; i += 8)
        tile[i][tx] = x[(size_t)(b0 + i) * T + t0 + tx];
    __syncthreads();
    #pragma unroll
    for (int i = ty; i < 32; i += 8)
        xT[(size_t)(t0 + i) * B + b0 + tx] = tile[tx][i];
}

// ---- persistent RNN (R4 structure; only the group barrier changed) ----
// 256 WGs x 256 threads (4 waves): WG = (group g, M-slice ms).
// Wave (wm,wn): rows [ms*64 + wm*32, +32), batches [g*32 + wn*16, +16).
// W in LDS in MFMA-fragment order (conflict-free b128 reads).
// h: agent-scope coherent stores (write-through to coherence point),
// plain CACHED loads + per-step acquire fence (invalidate-only) by wave 0.
// Barrier: per-WG flag STORE (16 parallel lines) + 16-lane parallel poll.
__global__ void __launch_bounds__(256, 1) rnn_persist(
        const _Float16* __restrict__ Wf, const float* __restrict__ xT,
        const float* __restrict__ Whx, const float* __restrict__ bh,
        _Float16* h0, _Float16* h1, unsigned* flags) {

    __shared__ _Float16 Wlds[MROWS * H];   // 128 KB -> 1 WG/CU, 4 waves/CU

    // XCD-aware swizzle (perf-only): co-locate each group's 16 WGs
    const int bid = blockIdx.x;
    const int xcd = bid & 7;
    const int j   = bid >> 3;              // 0..31
    const int g   = (xcd << 1) | (j >> 4); // group 0..15
    const int ms  = j & 15;                // M slice 0..15

    const int tid  = threadIdx.x;
    const int wave = tid >> 6;
    const int lane = tid & 63;
    const int wm   = wave >> 1;            // M half 0..1
    const int wn   = wave & 1;             // N half 0..1
    const int lm   = lane & 15;
    const int kg   = lane >> 4;

    // ---- stage W into fragment-order LDS ----
    for (int f = tid; f < MROWS * H / 8; f += 256) {
        const int p   = f >> 6;
        const int l   = f & 63;
        const int kkb = p >> 2;
        const int pwm = (p >> 1) & 1;
        const int prb = p & 1;
        const int pkg = l >> 4;
        const int plm = l & 15;
        const int m = ms * 64 + pwm * 32 + prb * 16 + plm;
        f16x8 v = *(const f16x8*)(Wf + (size_t)m * H + kkb * 32 + pkg * 8);
        *(f16x8*)((char*)Wlds + (size_t)f * 16) = v;
    }
    __syncthreads();

    // ---- per-lane constants ----
    const int n      = g * NSLICE + wn * 16 + lm;   // batch column
    const int base32 = ms * 64 + wm * 32;
    float whx0[4], whx1[4];
    #pragma unroll
    for (int r = 0; r < 4; ++r) {
        whx0[r] = Whx[base32 + kg * 4 + r];
        whx1[r] = Whx[base32 + 16 + kg * 4 + r];
    }
    const float bhn = bh[n];
    // consumer B-frag byte offsets within each 64B block (fragment-order h)
    const int off0 = ((kg & 1) << 5) | ((kg >> 1) << 3);

    const char* hin  = (const char*)h0;
    char*       hout = (char*)h1;
    unsigned* fme   = flags + (size_t)((g << 4) | ms) * FLAG_STRIDE;
    unsigned* fpoll = flags + (size_t)((g << 4) | (lane & 15)) * FLAG_STRIDE;

    for (int t = 0; t < T; ++t) {
        f32x4 acc0 = {0.f, 0.f, 0.f, 0.f};
        f32x4 acc1 = {0.f, 0.f, 0.f, 0.f};
        const char* brow = hin + (size_t)n * 2048;
        const char* arow = (const char*)Wlds + wm * 2048 + lane * 16;

        #pragma unroll 8
        for (int kb = 0; kb < 32; ++kb) {
            f16x8 a0 = *(const f16x8*)(arow + kb * 4096);
            f16x8 a1 = *(const f16x8*)(arow + kb * 4096 + 1024);
            union { unsigned long long u[2]; f16x8 v; } bb;
            bb.u[0] = *(const unsigned long long*)(brow + kb * 64 + off0);
            bb.u[1] = *(const unsigned long long*)(brow + kb * 64 + off0 + 16);
            acc0 = __builtin_amdgcn_mfma_f32_16x16x32_f16(a0, bb.v, acc0, 0, 0, 0);
            acc1 = __builtin_amdgcn_mfma_f32_16x16x32_f16(a1, bb.v, acc1, 0, 0, 0);
        }

        // ---- epilogue: rank-1 input + bias + tanh ----
        const float xn = xT[(size_t)t * B + n];
        union { unsigned long long u; f16x4 v; } s0, s1;
        #pragma unroll
        for (int r = 0; r < 4; ++r)
            s0.v[r] = (_Float16)fast_tanh(acc0[r] + whx0[r] * xn + bhn);
        #pragma unroll
        for (int r = 0; r < 4; ++r)
            s1.v[r] = (_Float16)fast_tanh(acc1[r] + whx1[r] * xn + bhn);
        // fragment-order store: 16B contiguous per lane, coherent write-through
        char* dst = hout + (size_t)n * 2048 + (ms * 2 + wm) * 64 + kg * 16;
        __hip_atomic_store((unsigned long long*)dst, s0.u,
                           __ATOMIC_RELAXED, __HIP_MEMORY_SCOPE_AGENT);
        __hip_atomic_store((unsigned long long*)(dst + 8), s1.u,
                           __ATOMIC_RELAXED, __HIP_MEMORY_SCOPE_AGENT);

        // ---- group barrier: per-WG flag store + parallel poll (no RMW) ----
        asm volatile("s_waitcnt vmcnt(0)" ::: "memory");   // this wave's h stores at MALL
        __syncthreads();                                   // all 4 waves done
        if (tid == 0)
            __hip_atomic_store(fme, (unsigned)(t + 1),
                               __ATOMIC_RELAXED, __HIP_MEMORY_SCOPE_AGENT);
        if (wave == 0) {
            unsigned v;
            do {
                __builtin_amdgcn_s_sleep(1);
                v = __hip_atomic_load(fpoll, __ATOMIC_RELAXED, __HIP_MEMORY_SCOPE_AGENT);
            } while (!__all((int)(v >= (unsigned)(t + 1))));
            // acquire: invalidate L1+L2 (nothing dirty -> no writeback storm)
            __builtin_amdgcn_fence(__ATOMIC_ACQUIRE, "agent");
        }
        __syncthreads();   // releases waves 1..3 after inv completes
        __builtin_amdgcn_sched_barrier(0);

        char* tmp = (char*)hin;
        hin = hout;
        hout = tmp;
    }
}

// ---- final projection (reads fragment-order h) ----
__global__ void proj_kernel(const _Float16* __restrict__ hbuf,
                            const float* __restrict__ Wph,
                            const float* __restrict__ bp,
                            float* __restrict__ out) {
    const int b = blockIdx.x;
    const int lane = threadIdx.x;  // 64
    float partial[NC];
    #pragma unroll
    for (int c = 0; c < NC; ++c) partial[c] = 0.f;
    for (int i = lane; i < H; i += 64) {
        const int inner = i & 31;           // element within 32-row block
        const int pkg = inner >> 3;
        const int prb = (inner >> 2) & 1;
        const int pr  = inner & 3;
        const int m = (i >> 5) * 32 + prb * 16 + pkg * 4 + pr;
        float hv = (float)hbuf[(size_t)b * H + i];
        #pragma unroll
        for (int c = 0; c < NC; ++c) partial[c] += Wph[(size_t)c * H + m] * hv;
    }
    #pragma unroll
    for (int c = 0; c < NC; ++c) {
        float v = partial[c];
        #pragma unroll
        for (int off = 32; off; off >>= 1) v += __shfl_down(v, off);
        if (lane == 0) out[(size_t)b * NC + c] = v + bp[b];
    }
}

extern "C" void kernel_launch(void* const* d_in, const int* in_sizes, int n_in,
                              void* d_out, int out_size, void* d_ws, size_t ws_size,
                              hipStream_t stream) {
    const float* x   = (const float*)d_in[0];
    const float* Whx = (const float*)d_in[1];
    const float* Whh = (const float*)d_in[2];
    const float* Wph = (const float*)d_in[3];
    const float* bh  = (const float*)d_in[4];
    const float* bp  = (const float*)d_in[5];
    float* out = (float*)d_out;

    char* ws = (char*)d_ws;
    _Float16* Wf  = (_Float16*)ws;                           // 2 MB
    _Float16* h0  = (_Float16*)(ws + (2u << 20));            // 1 MB
    _Float16* h1  = (_Float16*)(ws + (3u << 20));            // 1 MB
    float*    xT  = (float*)(ws + (4u << 20));               // 1 MB
    unsigned* flags = (unsigned*)(ws + (5u << 20));          // 256 x 64B

    convert_w<<<(H * H / 4) / 256, 256, 0, stream>>>(Whh, Wf);
    transpose_x<<<dim3(T / 32, B / 32), 256, 0, stream>>>(x, xT);
    hipMemsetAsync(h0, 0, (size_t)B * H * 2, stream);
    hipMemsetAsync(flags, 0, NGROUPS * WPG * FLAG_STRIDE * sizeof(unsigned), stream);

    rnn_persist<<<NGROUPS * WPG, 256, 0, stream>>>(Wf, xT, Whx, bh, h0, h1, flags);

    // T even -> final h back in h0
    proj_kernel<<<B, 64, 0, stream>>>(h0, Wph, bp, out);
}

// Round 8
// 3473.738 us; speedup vs baseline: 5.7592x; 1.4680x over previous
//
#include <hip/hip_runtime.h>
#include <hip/hip_fp16.h>

#define H 1024
#define B 512
#define T 512
#define NC 10

#define NGROUPS 16      // batch-slice groups (32 batches each)
#define WPG 16          // WGs per group (M slices)
#define NSLICE 32       // batches per group
#define MROWS 64        // H rows per WG
#define FLAG_STRIDE 16  // 64B-padded flag per (WG,wave)

typedef _Float16 f16x8 __attribute__((ext_vector_type(8)));
typedef _Float16 f16x4 __attribute__((ext_vector_type(4)));
typedef float    f32x4 __attribute__((ext_vector_type(4)));
typedef unsigned u32x4 __attribute__((ext_vector_type(4)));
typedef unsigned long long ull;

__device__ __forceinline__ float fast_tanh(float x) {
    float e = __expf(2.0f * x);
    return 1.0f - 2.0f / (e + 1.0f);
}

// ---- W_hh f32 -> f16 row-major ----
__global__ void convert_w(const float* __restrict__ w, _Float16* __restrict__ o) {
    int i = (blockIdx.x * 256 + threadIdx.x) * 4;
    float4 v = *(const float4*)(w + i);
    f16x4 r;
    r[0] = (_Float16)v.x; r[1] = (_Float16)v.y;
    r[2] = (_Float16)v.z; r[3] = (_Float16)v.w;
    *(f16x4*)(o + i) = r;
}

// ---- x [B][T] -> xT [T][B] ----
__global__ void transpose_x(const float* __restrict__ x, float* __restrict__ xT) {
    __shared__ float tile[32][33];
    const int tx = threadIdx.x & 31;
    const int ty = threadIdx.x >> 5;
    const int t0 = blockIdx.x * 32;
    const int b0 = blockIdx.y * 32;
    #pragma unroll
    for (int i = ty; i < 32; i += 8)
        tile[i][tx] = x[(size_t)(b0 + i) * T + t0 + tx];
    __syncthreads();
    #pragma unroll
    for (int i = ty; i < 32; i += 8)
        xT[(size_t)(t0 + i) * B + b0 + tx] = tile[tx][i];
}

// MALL-coherent load (proven path, R3): bypass L1 AND L2, read coherence point
#define G_LOAD_X4(dst, addr, OFF) \
    asm volatile("global_load_dwordx4 %0, %1, off offset:" OFF " sc0 sc1" \
                 : "=&v"(dst) : "v"(addr) : "memory")

#define ISSUE8(arr, base) do { \
    G_LOAD_X4(arr[0], (base), "0");   G_LOAD_X4(arr[1], (base), "64");  \
    G_LOAD_X4(arr[2], (base), "128"); G_LOAD_X4(arr[3], (base), "192"); \
    G_LOAD_X4(arr[4], (base), "256"); G_LOAD_X4(arr[5], (base), "320"); \
    G_LOAD_X4(arr[6], (base), "384"); G_LOAD_X4(arr[7], (base), "448"); \
} while (0)

// ---- persistent RNN: 256 WGs x 256 thr (4 waves) ----
// Wave (wm,wn) of WG(g,ms): rows [ms*64+wm*32,+32), batches [g*32+wn*16,+16).
// W in LDS fragment-order. h row-major [n][m], ping-pong 2 buffers.
// ALL cross-CU traffic via MALL (sc0 sc1) — proven coherent; NO fences,
// NO syncthreads in loop: per-wave flags, each wave polls its 32 producers.
__global__ void __launch_bounds__(256, 1) rnn_persist(
        const _Float16* __restrict__ Wf, const float* __restrict__ xT,
        const float* __restrict__ Whx, const float* __restrict__ bh,
        _Float16* h0, _Float16* h1, unsigned* flags) {

    __shared__ _Float16 Wlds[MROWS * H];   // 128 KB -> 1 WG/CU

    // static XCD swizzle (perf heuristic only; MALL is scope-correct anyway)
    const int bid = blockIdx.x;
    const int xcd = bid & 7;
    const int j   = bid >> 3;
    const int g   = (xcd << 1) | (j >> 4); // group 0..15
    const int ms  = j & 15;                // M slice 0..15

    const int tid  = threadIdx.x;
    const int wave = tid >> 6;
    const int lane = tid & 63;
    const int lm   = lane & 15;
    const int kg   = lane >> 4;
    const int wm   = wave >> 1;            // M half 0..1
    const int wn   = wave & 1;             // N half 0..1

    // ---- stage W rows [ms*64,+64) into fragment-order LDS ----
    for (int f = tid; f < MROWS * H / 8; f += 256) {
        const int p   = f >> 6;
        const int l   = f & 63;
        const int kkb = p >> 2;
        const int pwm = (p >> 1) & 1;
        const int prb = p & 1;
        const int pkg = l >> 4;
        const int plm = l & 15;
        const int m = ms * 64 + pwm * 32 + prb * 16 + plm;
        f16x8 v = *(const f16x8*)(Wf + (size_t)m * H + kkb * 32 + pkg * 8);
        *(f16x8*)((char*)Wlds + (size_t)f * 16) = v;
    }
    __syncthreads();   // once, before the loop

    // ---- per-lane constants ----
    const int n      = g * NSLICE + wn * 16 + lm;   // batch column
    const int base32 = ms * 64 + wm * 32;
    float whx0[4], whx1[4];
    #pragma unroll
    for (int r = 0; r < 4; ++r) {
        whx0[r] = Whx[base32 + kg * 4 + r];
        whx1[r] = Whx[base32 + 16 + kg * 4 + r];
    }
    const float bhn = bh[n];

    const ull hu0 = (ull)h0, hu1 = (ull)h1;
    const char* arow = (const char*)Wlds + wm * 2048 + lane * 16;

    // my flag: (g, ms, wm, wn); producers I wait on: (g, ms', wm', wn)
    unsigned* fme = flags +
        (size_t)((((g << 4) | ms) << 2) | (wm << 1) | wn) * FLAG_STRIDE;
    const unsigned* fpoll = flags +
        (size_t)((((g << 4) | ((lane >> 1) & 15)) << 2) | ((lane & 1) << 1) | wn)
        * FLAG_STRIDE;

    #define COMPUTE8(arr, KB0)                                            \
        _Pragma("unroll")                                                 \
        for (int i = 0; i < 8; ++i) {                                     \
            f16x8 a0 = *(const f16x8*)(arow + (KB0 + i) * 4096);          \
            f16x8 a1 = *(const f16x8*)(arow + (KB0 + i) * 4096 + 1024);   \
            union { u32x4 u; f16x8 v; } bb; bb.u = arr[i];                \
            acc0 = __builtin_amdgcn_mfma_f32_16x16x32_f16(a0, bb.v, acc0, 0, 0, 0); \
            acc1 = __builtin_amdgcn_mfma_f32_16x16x32_f16(a1, bb.v, acc1, 0, 0, 0); \
        }

    for (int t = 0; t < T; ++t) {
        // ---- wait for h(t): my 32 producers' flags >= t (trivially true at t=0) ----
        for (;;) {
            unsigned v = __hip_atomic_load(fpoll, __ATOMIC_RELAXED,
                                           __HIP_MEMORY_SCOPE_AGENT);
            if (__all((int)(v >= (unsigned)t))) break;
            __builtin_amdgcn_s_sleep(1);
        }
        __builtin_amdgcn_sched_barrier(0);

        const ull rdb = (t & 1) ? hu1 : hu0;
        const ull wrb = (t & 1) ? hu0 : hu1;
        const ull rd  = rdb + (size_t)n * 2048 + kg * 16;

        u32x4 hA[8], hB[8];
        f32x4 acc0 = {0.f, 0.f, 0.f, 0.f};
        f32x4 acc1 = {0.f, 0.f, 0.f, 0.f};

        ISSUE8(hA, rd);
        ISSUE8(hB, rd + 512);
        asm volatile("s_waitcnt vmcnt(8)" ::: "memory");
        __builtin_amdgcn_sched_barrier(0);
        COMPUTE8(hA, 0);
        ISSUE8(hA, rd + 1024);
        asm volatile("s_waitcnt vmcnt(8)" ::: "memory");
        __builtin_amdgcn_sched_barrier(0);
        COMPUTE8(hB, 8);
        ISSUE8(hB, rd + 1536);
        asm volatile("s_waitcnt vmcnt(8)" ::: "memory");
        __builtin_amdgcn_sched_barrier(0);
        COMPUTE8(hA, 16);
        asm volatile("s_waitcnt vmcnt(0)" ::: "memory");
        __builtin_amdgcn_sched_barrier(0);
        COMPUTE8(hB, 24);

        // ---- epilogue: rank-1 input + bias + tanh; MALL-coherent stores ----
        const float xn = xT[(size_t)t * B + n];
        union { ull u; f16x4 v; } s0, s1;
        #pragma unroll
        for (int r = 0; r < 4; ++r)
            s0.v[r] = (_Float16)fast_tanh(acc0[r] + whx0[r] * xn + bhn);
        #pragma unroll
        for (int r = 0; r < 4; ++r)
            s1.v[r] = (_Float16)fast_tanh(acc1[r] + whx1[r] * xn + bhn);
        // h row-major [n][m]: s0 rows at m=base32+kg*4 (8B), s1 at m+16 (+32B)
        const ull wr = wrb + (size_t)n * 2048 + (size_t)(base32 + kg * 4) * 2;
        __hip_atomic_store((ull*)wr, s0.u,
                           __ATOMIC_RELAXED, __HIP_MEMORY_SCOPE_AGENT);
        __hip_atomic_store((ull*)(wr + 32), s1.u,
                           __ATOMIC_RELAXED, __HIP_MEMORY_SCOPE_AGENT);

        // ---- signal: my h(t+1) slice is at the coherence point ----
        asm volatile("s_waitcnt vmcnt(0)" ::: "memory");  // reads+stores drained
        if (lane == 0)
            __hip_atomic_store(fme, (unsigned)(t + 1),
                               __ATOMIC_RELAXED, __HIP_MEMORY_SCOPE_AGENT);
        __builtin_amdgcn_sched_barrier(0);
    }
    #undef COMPUTE8
}

// ---- final projection: h plain row-major [B][H] ----
__global__ void proj_kernel(const _Float16* __restrict__ hT,
                            const float* __restrict__ Wph,
                            const float* __restrict__ bp,
                            float* __restrict__ out) {
    const int b = blockIdx.x;
    const int lane = threadIdx.x;  // 64
    float partial[NC];
    #pragma unroll
    for (int c = 0; c < NC; ++c) partial[c] = 0.f;
    for (int i = lane; i < H; i += 64) {
        float hv = (float)hT[(size_t)b * H + i];
        #pragma unroll
        for (int c = 0; c < NC; ++c) partial[c] += Wph[(size_t)c * H + i] * hv;
    }
    #pragma unroll
    for (int c = 0; c < NC; ++c) {
        float v = partial[c];
        #pragma unroll
        for (int off = 32; off; off >>= 1) v += __shfl_down(v, off);
        if (lane == 0) out[(size_t)b * NC + c] = v + bp[b];
    }
}

extern "C" void kernel_launch(void* const* d_in, const int* in_sizes, int n_in,
                              void* d_out, int out_size, void* d_ws, size_t ws_size,
                              hipStream_t stream) {
    const float* x   = (const float*)d_in[0];
    const float* Whx = (const float*)d_in[1];
    const float* Whh = (const float*)d_in[2];
    const float* Wph = (const float*)d_in[3];
    const float* bh  = (const float*)d_in[4];
    const float* bp  = (const float*)d_in[5];
    float* out = (float*)d_out;

    char* ws = (char*)d_ws;
    _Float16* Wf    = (_Float16*)ws;                     // 2 MB
    _Float16* h0    = (_Float16*)(ws + (2u << 20));      // 1 MB
    _Float16* h1    = (_Float16*)(ws + (3u << 20));      // 1 MB
    float*    xT    = (float*)(ws + (4u << 20));         // 1 MB
    unsigned* flags = (unsigned*)(ws + (5u << 20));      // 1024 x 64 B

    convert_w<<<(H * H / 4) / 256, 256, 0, stream>>>(Whh, Wf);
    transpose_x<<<dim3(T / 32, B / 32), 256, 0, stream>>>(x, xT);
    hipMemsetAsync(h0, 0, (size_t)B * H * 2, stream);
    hipMemsetAsync(flags, 0, 1024 * FLAG_STRIDE * sizeof(unsigned), stream);

    rnn_persist<<<NGROUPS * WPG, 256, 0, stream>>>(Wf, xT, Whx, bh, h0, h1, flags);

    // T even -> final h in h0
    proj_kernel<<<B, 64, 0, stream>>>(h0, Wph, bp, out);
}

// Round 9
// 3253.215 us; speedup vs baseline: 6.1495x; 1.0678x over previous
//
#include <hip/hip_runtime.h>
#include <hip/hip_fp16.h>

#define H 1024
#define B 512
#define T 512
#define NC 10

#define NGROUPS 16      // batch-slice groups (32 batches each)
#define WPG 16          // WGs per group (M slices)
#define NSLICE 32       // batches per group
#define MROWS 64        // H rows per WG
#define FLAG_STRIDE 16  // 64B-padded flag per (WG,wave)

typedef _Float16 f16x8 __attribute__((ext_vector_type(8)));
typedef _Float16 f16x4 __attribute__((ext_vector_type(4)));
typedef float    f32x4 __attribute__((ext_vector_type(4)));
typedef unsigned u32x4 __attribute__((ext_vector_type(4)));
typedef unsigned long long ull;

__device__ __forceinline__ float fast_tanh(float x) {
    float e = __expf(2.0f * x);
    return 1.0f - 2.0f / (e + 1.0f);
}

// ---- W_hh f32 -> f16 row-major ----
__global__ void convert_w(const float* __restrict__ w, _Float16* __restrict__ o) {
    int i = (blockIdx.x * 256 + threadIdx.x) * 4;
    float4 v = *(const float4*)(w + i);
    f16x4 r;
    r[0] = (_Float16)v.x; r[1] = (_Float16)v.y;
    r[2] = (_Float16)v.z; r[3] = (_Float16)v.w;
    *(f16x4*)(o + i) = r;
}

// ---- x [B][T] -> xT [T][B] ----
__global__ void transpose_x(const float* __restrict__ x, float* __restrict__ xT) {
    __shared__ float tile[32][33];
    const int tx = threadIdx.x & 31;
    const int ty = threadIdx.x >> 5;
    const int t0 = blockIdx.x * 32;
    const int b0 = blockIdx.y * 32;
    #pragma unroll
    for (int i = ty; i < 32; i += 8)
        tile[i][tx] = x[(size_t)(b0 + i) * T + t0 + tx];
    __syncthreads();
    #pragma unroll
    for (int i = ty; i < 32; i += 8)
        xT[(size_t)(t0 + i) * B + b0 + tx] = tile[tx][i];
}

// h load: sc0 only -> bypass own stale L1, served by the XCD-shared L2
#define G_LOAD_X4(dst, addr, OFF) \
    asm volatile("global_load_dwordx4 %0, %1, off offset:" OFF " sc0" \
                 : "=&v"(dst) : "v"(addr) : "memory")

#define ISSUE8(arr, base) do { \
    G_LOAD_X4(arr[0], (base), "0");   G_LOAD_X4(arr[1], (base), "64");  \
    G_LOAD_X4(arr[2], (base), "128"); G_LOAD_X4(arr[3], (base), "192"); \
    G_LOAD_X4(arr[4], (base), "256"); G_LOAD_X4(arr[5], (base), "320"); \
    G_LOAD_X4(arr[6], (base), "384"); G_LOAD_X4(arr[7], (base), "448"); \
} while (0)

// h store: sc0 -> coherent write-through to the XCD-shared L2 (stops at L2)
#define G_STORE_X2(addr, data) \
    asm volatile("global_store_dwordx2 %0, %1, off sc0" \
                 :: "v"(addr), "v"(data) : "memory")

// ---- persistent RNN: 256 WGs x 256 thr (4 waves) ----
// Groups formed dynamically per XCD (1 WG/CU forced by 128KB LDS; grid=CUs
// => exactly 32 WGs/XCD => 2 groups of 16 WGs per XCD, all sharing one L2).
// h exchange entirely inside the XCD L2 (sc0 stores + sc0 loads).
// Flags on the R8-proven MALL path (agent-scope atomics): h stores ack at L2
// (vmcnt 0) BEFORE the flag's >=900cy MALL trip => flag=t+1 implies h visible.
__global__ void __launch_bounds__(256, 1) rnn_persist(
        const _Float16* __restrict__ Wf, const float* __restrict__ xT,
        const float* __restrict__ Whx, const float* __restrict__ bh,
        _Float16* h0, _Float16* h1, unsigned* flags, unsigned* claim) {

    __shared__ _Float16 Wlds[MROWS * H];   // 128 KB -> exactly 1 WG/CU
    __shared__ int s_g, s_ms;

    const int tid  = threadIdx.x;
    const int wave = tid >> 6;
    const int lane = tid & 63;
    const int lm   = lane & 15;
    const int kg   = lane >> 4;
    const int wm   = wave >> 1;            // M half 0..1
    const int wn   = wave & 1;             // N half 0..1

    // ---- dynamic XCD grouping (capacity-forced: exactly 32 WGs per XCD) ----
    if (tid == 0) {
        unsigned xcd;
        asm volatile("s_getreg_b32 %0, hwreg(HW_REG_XCC_ID)" : "=s"(xcd));
        xcd &= 7;
        unsigned slot = atomicAdd(&claim[xcd], 1u);   // 0..31 per XCD
        s_ms = (int)(slot & 15);
        s_g  = (int)(xcd * 2 + (slot >> 4));
    }
    __syncthreads();
    const int g  = s_g;
    const int ms = s_ms;

    // ---- stage W rows [ms*64,+64) into fragment-order LDS ----
    for (int f = tid; f < MROWS * H / 8; f += 256) {
        const int p   = f >> 6;
        const int l   = f & 63;
        const int kkb = p >> 2;
        const int pwm = (p >> 1) & 1;
        const int prb = p & 1;
        const int pkg = l >> 4;
        const int plm = l & 15;
        const int m = ms * 64 + pwm * 32 + prb * 16 + plm;
        f16x8 v = *(const f16x8*)(Wf + (size_t)m * H + kkb * 32 + pkg * 8);
        *(f16x8*)((char*)Wlds + (size_t)f * 16) = v;
    }
    __syncthreads();   // once, before the loop

    // ---- per-lane constants ----
    const int n      = g * NSLICE + wn * 16 + lm;   // batch column
    const int base32 = ms * 64 + wm * 32;
    float whx0[4], whx1[4];
    #pragma unroll
    for (int r = 0; r < 4; ++r) {
        whx0[r] = Whx[base32 + kg * 4 + r];
        whx1[r] = Whx[base32 + 16 + kg * 4 + r];
    }
    const float bhn = bh[n];

    const ull hu0 = (ull)h0, hu1 = (ull)h1;
    const char* arow = (const char*)Wlds + wm * 2048 + lane * 16;

    // my flag: (g, ms, wm, wn); producers I wait on: (g, ms', wm', wn)
    unsigned* fme = flags +
        (size_t)((((g << 4) | ms) << 2) | (wm << 1) | wn) * FLAG_STRIDE;
    const unsigned* fpoll = flags +
        (size_t)((((g << 4) | ((lane >> 1) & 15)) << 2) | ((lane & 1) << 1) | wn)
        * FLAG_STRIDE;

    #define COMPUTE8(arr, KB0)                                            \
        _Pragma("unroll")                                                 \
        for (int i = 0; i < 8; ++i) {                                     \
            f16x8 a0 = *(const f16x8*)(arow + (KB0 + i) * 4096);          \
            f16x8 a1 = *(const f16x8*)(arow + (KB0 + i) * 4096 + 1024);   \
            union { u32x4 u; f16x8 v; } bb; bb.u = arr[i];                \
            acc0 = __builtin_amdgcn_mfma_f32_16x16x32_f16(a0, bb.v, acc0, 0, 0, 0); \
            acc1 = __builtin_amdgcn_mfma_f32_16x16x32_f16(a1, bb.v, acc1, 0, 0, 0); \
        }

    for (int t = 0; t < T; ++t) {
        // ---- wait for h(t): my 32 producers' flags >= t (trivially true at t=0) ----
        for (;;) {
            unsigned v = __hip_atomic_load(fpoll, __ATOMIC_RELAXED,
                                           __HIP_MEMORY_SCOPE_AGENT);
            if (__all((int)(v >= (unsigned)t))) break;
            __builtin_amdgcn_s_sleep(1);
        }
        __builtin_amdgcn_sched_barrier(0);

        const ull rdb = (t & 1) ? hu1 : hu0;
        const ull wrb = (t & 1) ? hu0 : hu1;
        const ull rd  = rdb + (size_t)n * 2048 + kg * 16;

        u32x4 hA[8], hB[8];
        f32x4 acc0 = {0.f, 0.f, 0.f, 0.f};
        f32x4 acc1 = {0.f, 0.f, 0.f, 0.f};

        ISSUE8(hA, rd);
        ISSUE8(hB, rd + 512);
        asm volatile("s_waitcnt vmcnt(8)" ::: "memory");
        __builtin_amdgcn_sched_barrier(0);
        COMPUTE8(hA, 0);
        ISSUE8(hA, rd + 1024);
        asm volatile("s_waitcnt vmcnt(8)" ::: "memory");
        __builtin_amdgcn_sched_barrier(0);
        COMPUTE8(hB, 8);
        ISSUE8(hB, rd + 1536);
        asm volatile("s_waitcnt vmcnt(8)" ::: "memory");
        __builtin_amdgcn_sched_barrier(0);
        COMPUTE8(hA, 16);
        asm volatile("s_waitcnt vmcnt(0)" ::: "memory");
        __builtin_amdgcn_sched_barrier(0);
        COMPUTE8(hB, 24);

        // ---- epilogue: rank-1 input + bias + tanh; sc0 stores (-> own L2) ----
        const float xn = xT[(size_t)t * B + n];
        union { ull u; f16x4 v; } s0, s1;
        #pragma unroll
        for (int r = 0; r < 4; ++r)
            s0.v[r] = (_Float16)fast_tanh(acc0[r] + whx0[r] * xn + bhn);
        #pragma unroll
        for (int r = 0; r < 4; ++r)
            s1.v[r] = (_Float16)fast_tanh(acc1[r] + whx1[r] * xn + bhn);
        // h row-major [n][m]: s0 rows at m=base32+kg*4 (8B), s1 at m+16 (+32B)
        const ull wr = wrb + (size_t)n * 2048 + (size_t)(base32 + kg * 4) * 2;
        G_STORE_X2(wr, s0.u);
        G_STORE_X2(wr + 32, s1.u);

        // ---- signal: h slice is in the XCD L2; flag via proven MALL path ----
        asm volatile("s_waitcnt vmcnt(0)" ::: "memory");  // reads+stores drained
        if (lane == 0)
            __hip_atomic_store(fme, (unsigned)(t + 1),
                               __ATOMIC_RELAXED, __HIP_MEMORY_SCOPE_AGENT);
        __builtin_amdgcn_sched_barrier(0);
    }
    #undef COMPUTE8
}

// ---- final projection: h plain row-major [B][H] ----
__global__ void proj_kernel(const _Float16* __restrict__ hT,
                            const float* __restrict__ Wph,
                            const float* __restrict__ bp,
                            float* __restrict__ out) {
    const int b = blockIdx.x;
    const int lane = threadIdx.x;  // 64
    float partial[NC];
    #pragma unroll
    for (int c = 0; c < NC; ++c) partial[c] = 0.f;
    for (int i = lane; i < H; i += 64) {
        float hv = (float)hT[(size_t)b * H + i];
        #pragma unroll
        for (int c = 0; c < NC; ++c) partial[c] += Wph[(size_t)c * H + i] * hv;
    }
    #pragma unroll
    for (int c = 0; c < NC; ++c) {
        float v = partial[c];
        #pragma unroll
        for (int off = 32; off; off >>= 1) v += __shfl_down(v, off);
        if (lane == 0) out[(size_t)b * NC + c] = v + bp[b];
    }
}

extern "C" void kernel_launch(void* const* d_in, const int* in_sizes, int n_in,
                              void* d_out, int out_size, void* d_ws, size_t ws_size,
                              hipStream_t stream) {
    const float* x   = (const float*)d_in[0];
    const float* Whx = (const float*)d_in[1];
    const float* Whh = (const float*)d_in[2];
    const float* Wph = (const float*)d_in[3];
    const float* bh  = (const float*)d_in[4];
    const float* bp  = (const float*)d_in[5];
    float* out = (float*)d_out;

    char* ws = (char*)d_ws;
    _Float16* Wf    = (_Float16*)ws;                     // 2 MB
    _Float16* h0    = (_Float16*)(ws + (2u << 20));      // 1 MB
    _Float16* h1    = (_Float16*)(ws + (3u << 20));      // 1 MB
    float*    xT    = (float*)(ws + (4u << 20));         // 1 MB
    unsigned* flags = (unsigned*)(ws + (5u << 20));      // 1024 x 64 B
    unsigned* claim = (unsigned*)(ws + (5u << 20) + 65536);

    convert_w<<<(H * H / 4) / 256, 256, 0, stream>>>(Whh, Wf);
    transpose_x<<<dim3(T / 32, B / 32), 256, 0, stream>>>(x, xT);
    hipMemsetAsync(h0, 0, (size_t)B * H * 2, stream);
    hipMemsetAsync(flags, 0, 65536 + 256, stream);

    rnn_persist<<<NGROUPS * WPG, 256, 0, stream>>>(Wf, xT, Whx, bh,
                                                   h0, h1, flags, claim);

    // T even -> final h in h0
    proj_kernel<<<B, 64, 0, stream>>>(h0, Wph, bp, out);
}